// Round 1
// baseline (209.806 us; speedup 1.0000x reference)
//
#include <hip/hip_runtime.h>
#include <stdint.h>

typedef short bf16x8 __attribute__((ext_vector_type(8)));
typedef float f32x4 __attribute__((ext_vector_type(4)));
typedef unsigned short u16;

#define MFMA_BF16 __builtin_amdgcn_mfma_f32_16x16x32_bf16
#define LOG2E 1.44269504088896f

static __device__ __forceinline__ u16 f2bf(float x) {
  union { float f; unsigned u; } v; v.f = x;
  unsigned r = v.u + 0x7fffu + ((v.u >> 16) & 1u);
  return (u16)(r >> 16);
}
static __device__ __forceinline__ float bf2f(u16 h) {
  union { unsigned u; float f; } v; v.u = ((unsigned)h) << 16; return v.f;
}
static __device__ __forceinline__ void gld_lds16(const u16* g, u16* l) {
  __builtin_amdgcn_global_load_lds(
      (const __attribute__((address_space(1))) void*)g,
      (__attribute__((address_space(3))) void*)l, 16, 0, 0);
}

// ---------------- cast fp32 -> bf16 (8 elems/thread) ----------------
__global__ __launch_bounds__(256) void k_cast(const float* __restrict__ x,
                                              u16* __restrict__ y) {
  int i = blockIdx.x * 256 + threadIdx.x;
  const float4* p = (const float4*)x;
  float4 a = p[i * 2], b = p[i * 2 + 1];
  ushort4 o0, o1;
  o0.x = f2bf(a.x); o0.y = f2bf(a.y); o0.z = f2bf(a.z); o0.w = f2bf(a.w);
  o1.x = f2bf(b.x); o1.y = f2bf(b.y); o1.z = f2bf(b.z); o1.w = f2bf(b.w);
  ushort4* q = (ushort4*)y;
  q[i * 2] = o0; q[i * 2 + 1] = o1;
}

// ---------------- transpose weight: w[K][N] fp32 -> wt[N][K] bf16 ----------------
__global__ __launch_bounds__(256) void k_wtrans(const float* __restrict__ w,
                                                u16* __restrict__ wt,
                                                int K, int N) {
  int n = blockIdx.x * 256 + threadIdx.x;
  int k0 = blockIdx.y * 8;
  if (n >= N) return;
  u16 o[8];
#pragma unroll
  for (int j = 0; j < 8; j++) o[j] = f2bf(w[(size_t)(k0 + j) * N + n]);
  *(uint4*)&wt[(size_t)n * K + k0] = *(const uint4*)o;
}

// ---------------- GEMM: C[M][N] = A[M][K] * Bt[N][K]^T + bias ----------------
// 128x128 tile, BK=64, 4 waves (2x2), 16x16x32 bf16 MFMA.
// LDS staged via global_load_lds w/ pre-swizzled global source; swizzled ds_read.
template <int OUT_BF16>
__global__ __launch_bounds__(256, 2) void k_gemm(const u16* __restrict__ A,
                                                 const u16* __restrict__ Bt,
                                                 const float* __restrict__ bias,
                                                 void* __restrict__ Cp,
                                                 int M, int N, int K) {
  __shared__ u16 As[128 * 64];
  __shared__ u16 Bs[128 * 64];
  const int tid = threadIdx.x;
  const int lane = tid & 63;
  const int wid = tid >> 6;
  const int wm = wid >> 1, wn = wid & 1;
  const int m0 = blockIdx.x * 128, n0 = blockIdx.y * 128;

  // staging: thread covers slots tid+256*i; slot s -> (row=s>>3, cslot=s&7),
  // content at (r,c) is global col-slot (c ^ (r&7))  [bijective swizzle]
  const int sr = tid >> 3;           // 0..31 (+32*i)
  const int sc = tid & 7;
  const int scsw = sc ^ (sr & 7);    // invariant under r+=32
  const u16* ga = A + (size_t)(m0 + sr) * K + (scsw << 3);
  const u16* gb = Bt + (size_t)(n0 + sr) * K + (scsw << 3);

  const int ar = wm * 64 + (lane & 15);
  const int br = wn * 64 + (lane & 15);
  const int cs0 = lane >> 4;

  f32x4 acc[4][4] = {};

  for (int k0 = 0; k0 < K; k0 += 64) {
    __syncthreads();
#pragma unroll
    for (int i = 0; i < 4; i++)
      gld_lds16(ga + k0 + i * (32 * K), &As[((tid & ~63) + 256 * i) * 8]);
#pragma unroll
    for (int i = 0; i < 4; i++)
      gld_lds16(gb + k0 + i * (32 * K), &Bs[((tid & ~63) + 256 * i) * 8]);
    __syncthreads();
#pragma unroll
    for (int kk = 0; kk < 2; kk++) {
      bf16x8 af[4], bfr[4];
#pragma unroll
      for (int mi = 0; mi < 4; mi++)
        af[mi] = *(const bf16x8*)&As[(ar + mi * 16) * 64 +
                                     (((kk * 4 + cs0) ^ (ar & 7)) << 3)];
#pragma unroll
      for (int ni = 0; ni < 4; ni++)
        bfr[ni] = *(const bf16x8*)&Bs[(br + ni * 16) * 64 +
                                      (((kk * 4 + cs0) ^ (br & 7)) << 3)];
#pragma unroll
      for (int mi = 0; mi < 4; mi++)
#pragma unroll
        for (int ni = 0; ni < 4; ni++)
          acc[mi][ni] = MFMA_BF16(af[mi], bfr[ni], acc[mi][ni], 0, 0, 0);
    }
  }

  const int crow0 = m0 + wm * 64 + ((lane >> 4) << 2);
  const int ccol0 = n0 + wn * 64 + (lane & 15);
#pragma unroll
  for (int ni = 0; ni < 4; ni++) {
    float bv = bias[ccol0 + ni * 16];
#pragma unroll
    for (int mi = 0; mi < 4; mi++) {
#pragma unroll
      for (int r = 0; r < 4; r++) {
        float v = acc[mi][ni][r] + bv;
        size_t idx = (size_t)(crow0 + mi * 16 + r) * N + ccol0 + ni * 16;
        if (OUT_BF16) ((u16*)Cp)[idx] = f2bf(v);
        else ((float*)Cp)[idx] = v;
      }
    }
  }
}

// ---------------- RMSNorm + RoPE for q,k; writes per-head [bh][n][d] ----------------
// Folds the 1/sqrt(d)=0.125 attention scale into Q (exact in bf16).
__global__ __launch_bounds__(256) void k_normrope(const u16* __restrict__ qkv,
                                                  const float* __restrict__ qscale,
                                                  const float* __restrict__ kscale,
                                                  u16* __restrict__ Qb,
                                                  u16* __restrict__ Kb) {
  const int row = blockIdx.x;  // b*2048+n
  const int b = row >> 11, n = row & 2047;
  const int t = threadIdx.x;
  __shared__ float qn[1024], kn[1024];
  __shared__ float csb[32], snb[32];
  __shared__ float redq[4], redk[4];

  ushort4 q4 = *(const ushort4*)&qkv[(size_t)row * 3072 + t * 4];
  ushort4 k4 = *(const ushort4*)&qkv[(size_t)row * 3072 + 1024 + t * 4];
  float qv[4] = {bf2f(q4.x), bf2f(q4.y), bf2f(q4.z), bf2f(q4.w)};
  float kv[4] = {bf2f(k4.x), bf2f(k4.y), bf2f(k4.z), bf2f(k4.w)};
  float sq = 0.f, sk = 0.f;
#pragma unroll
  for (int j = 0; j < 4; j++) { sq += qv[j] * qv[j]; sk += kv[j] * kv[j]; }
#pragma unroll
  for (int o = 1; o < 64; o <<= 1) {
    sq += __shfl_xor(sq, o);
    sk += __shfl_xor(sk, o);
  }
  if ((t & 63) == 0) { redq[t >> 6] = sq; redk[t >> 6] = sk; }
  if (t < 32) {
    float inv = exp2f(-(float)t * (13.287712379549449f / 32.f)); // 10000^(-t/32)
    float fr = (float)n * inv;
    float s, c;
    sincosf(fr, &s, &c);
    csb[t] = c; snb[t] = s;
  }
  __syncthreads();
  float rq = rsqrtf((redq[0] + redq[1] + redq[2] + redq[3]) * (1.f / 1024.f) + 1e-6f);
  float rk = rsqrtf((redk[0] + redk[1] + redk[2] + redk[3]) * (1.f / 1024.f) + 1e-6f);
#pragma unroll
  for (int j = 0; j < 4; j++) {
    int jj = t * 4 + j;
    qn[jj] = qv[j] * rq * qscale[jj];
    kn[jj] = kv[j] * rk * kscale[jj];
  }
  __syncthreads();
  const int j0 = t * 4;
  const int h = j0 >> 6;
  const int d0 = j0 & 63;
  u16 qo[4], ko[4];
#pragma unroll
  for (int j = 0; j < 4; j++) {
    int jj = j0 + j;
    int dd = d0 + j;
    float c = csb[dd & 31], s = snb[dd & 31];
    float oq, ok;
    if (dd < 32) {
      oq = qn[jj] * c - qn[jj + 32] * s;
      ok = kn[jj] * c - kn[jj + 32] * s;
    } else {
      oq = qn[jj] * c + qn[jj - 32] * s;
      ok = kn[jj] * c + kn[jj - 32] * s;
    }
    qo[j] = f2bf(oq * 0.125f);  // fold logit scale into Q
    ko[j] = f2bf(ok);
  }
  const size_t base = ((size_t)(b * 16 + h) * 2048 + n) * 64 + d0;
  *(ushort4*)&Qb[base] = *(const ushort4*)qo;
  *(ushort4*)&Kb[base] = *(const ushort4*)ko;
}

// ---------------- V transpose per head: qkv v-part -> Vt[bh][d=64][n=2048] ----------------
__global__ __launch_bounds__(256) void k_vtrans(const u16* __restrict__ qkv,
                                                u16* __restrict__ Vt) {
  const int bh = blockIdx.y;
  const int b = bh >> 4, h = bh & 15;
  const int n0 = blockIdx.x * 64;
  const int t = threadIdx.x;
  __shared__ u16 tile[64][72];  // [n][d] padded
#pragma unroll
  for (int i = 0; i < 2; i++) {
    int r = (t >> 3) + 32 * i;  // n within tile
    int c = t & 7;              // d slot
    uint4 v = *(const uint4*)&qkv[((size_t)(b * 2048 + n0 + r)) * 3072 + 2048 + h * 64 + c * 8];
    *(uint4*)&tile[r][c * 8] = v;
  }
  __syncthreads();
#pragma unroll
  for (int i = 0; i < 2; i++) {
    int dr = (t >> 3) + 32 * i;  // d
    int c = t & 7;               // n slot
    u16 vals[8];
#pragma unroll
    for (int j = 0; j < 8; j++) vals[j] = tile[c * 8 + j][dr];
    *(uint4*)&Vt[((size_t)bh * 64 + dr) * 2048 + n0 + c * 8] = *(const uint4*)vals;
  }
}

// ---------------- flash attention ----------------
// grid (16 q-tiles, 32 bh); 4 waves; wave owns 32 q-rows; BKV=64.
__global__ __launch_bounds__(256, 2) void k_attn(const u16* __restrict__ Qb,
                                                 const u16* __restrict__ Kb,
                                                 const u16* __restrict__ Vt,
                                                 u16* __restrict__ Ob) {
  const int bh = blockIdx.y;
  const int q0 = blockIdx.x * 128;
  const int t = threadIdx.x, lane = t & 63, wid = t >> 6;
  __shared__ u16 Ks[64 * 64];
  __shared__ u16 Vs[64 * 64];
  __shared__ u16 Ps[4][32 * 72];  // per-wave P, pad->stride 144B (16B aligned)
  const u16* Qg = Qb + (size_t)bh * 2048 * 64;
  const u16* Kg = Kb + (size_t)bh * 2048 * 64;
  const u16* Vg = Vt + (size_t)bh * 64 * 2048;

  bf16x8 qf[2][2];
#pragma unroll
  for (int mi = 0; mi < 2; mi++)
#pragma unroll
    for (int kk = 0; kk < 2; kk++)
      qf[mi][kk] = *(const bf16x8*)&Qg[(size_t)(q0 + wid * 32 + mi * 16 + (lane & 15)) * 64 +
                                       kk * 32 + ((lane >> 4) << 3)];

  f32x4 o[2][4] = {};
  float mrun[2][4], lrun[2][4];
#pragma unroll
  for (int mi = 0; mi < 2; mi++)
#pragma unroll
    for (int r = 0; r < 4; r++) { mrun[mi][r] = -1e30f; lrun[mi][r] = 0.f; }

  const int sr = t >> 3, sc = t & 7;
  const int scsw = sc ^ (sr & 7);
  const u16* gk = Kg + sr * 64 + (scsw << 3);
  const u16* gv = Vg + sr * 2048 + (scsw << 3);
  const int cs0 = lane >> 4;

  for (int kv0 = 0; kv0 < 2048; kv0 += 64) {
    __syncthreads();
#pragma unroll
    for (int i = 0; i < 2; i++)
      gld_lds16(gk + (size_t)(kv0 + i * 32) * 64, &Ks[((t & ~63) + 256 * i) * 8]);
#pragma unroll
    for (int i = 0; i < 2; i++)
      gld_lds16(gv + kv0 + (size_t)(i * 32) * 2048, &Vs[((t & ~63) + 256 * i) * 8]);
    __syncthreads();

    // S = Q K^T  (scale pre-folded into Q)
    f32x4 s[2][4] = {};
#pragma unroll
    for (int kk = 0; kk < 2; kk++) {
      bf16x8 kf[4];
#pragma unroll
      for (int nj = 0; nj < 4; nj++) {
        int kr = nj * 16 + (lane & 15);
        kf[nj] = *(const bf16x8*)&Ks[kr * 64 + (((kk * 4 + cs0) ^ (kr & 7)) << 3)];
      }
#pragma unroll
      for (int mi = 0; mi < 2; mi++)
#pragma unroll
        for (int nj = 0; nj < 4; nj++)
          s[mi][nj] = MFMA_BF16(qf[mi][kk], kf[nj], s[mi][nj], 0, 0, 0);
    }

    // online softmax (rows live in 16-lane groups sharing lane>>4)
#pragma unroll
    for (int mi = 0; mi < 2; mi++) {
      float mx[4], al[4], ls[4];
#pragma unroll
      for (int r = 0; r < 4; r++) {
        mx[r] = s[mi][0][r];
#pragma unroll
        for (int nj = 1; nj < 4; nj++) mx[r] = fmaxf(mx[r], s[mi][nj][r]);
      }
#pragma unroll
      for (int st = 1; st < 16; st <<= 1)
#pragma unroll
        for (int r = 0; r < 4; r++) mx[r] = fmaxf(mx[r], __shfl_xor(mx[r], st));
#pragma unroll
      for (int r = 0; r < 4; r++) {
        float mn = fmaxf(mrun[mi][r], mx[r]);
        al[r] = exp2f((mrun[mi][r] - mn) * LOG2E);
        mrun[mi][r] = mn;
        ls[r] = 0.f;
      }
#pragma unroll
      for (int nj = 0; nj < 4; nj++)
#pragma unroll
        for (int r = 0; r < 4; r++) {
          float p = exp2f((s[mi][nj][r] - mrun[mi][r]) * LOG2E);
          s[mi][nj][r] = p;
          ls[r] += p;
        }
#pragma unroll
      for (int st = 1; st < 16; st <<= 1)
#pragma unroll
        for (int r = 0; r < 4; r++) ls[r] += __shfl_xor(ls[r], st);
#pragma unroll
      for (int r = 0; r < 4; r++) lrun[mi][r] = lrun[mi][r] * al[r] + ls[r];
#pragma unroll
      for (int dj = 0; dj < 4; dj++)
#pragma unroll
        for (int r = 0; r < 4; r++) o[mi][dj][r] *= al[r];
#pragma unroll
      for (int nj = 0; nj < 4; nj++)
#pragma unroll
        for (int r = 0; r < 4; r++)
          Ps[wid][(mi * 16 + ((lane >> 4) << 2) + r) * 72 + nj * 16 + (lane & 15)] =
              f2bf(s[mi][nj][r]);
    }

    // O += P V
#pragma unroll
    for (int ks = 0; ks < 2; ks++) {
      bf16x8 pa[2], vb[4];
#pragma unroll
      for (int mi = 0; mi < 2; mi++)
        pa[mi] = *(const bf16x8*)&Ps[wid][(mi * 16 + (lane & 15)) * 72 +
                                          ((ks * 4 + cs0) << 3)];
#pragma unroll
      for (int dj = 0; dj < 4; dj++) {
        int vr = dj * 16 + (lane & 15);
        vb[dj] = *(const bf16x8*)&Vs[vr * 64 + (((ks * 4 + cs0) ^ (vr & 7)) << 3)];
      }
#pragma unroll
      for (int mi = 0; mi < 2; mi++)
#pragma unroll
        for (int dj = 0; dj < 4; dj++)
          o[mi][dj] = MFMA_BF16(pa[mi], vb[dj], o[mi][dj], 0, 0, 0);
    }
  }

  const int b = bh >> 4, h = bh & 15;
#pragma unroll
  for (int mi = 0; mi < 2; mi++)
#pragma unroll
    for (int r = 0; r < 4; r++) {
      float invl = 1.f / lrun[mi][r];
      int rowq = q0 + wid * 32 + mi * 16 + ((lane >> 4) << 2) + r;
#pragma unroll
      for (int dj = 0; dj < 4; dj++) {
        int col = h * 64 + dj * 16 + (lane & 15);
        Ob[(size_t)(b * 2048 + rowq) * 1024 + col] = f2bf(o[mi][dj][r] * invl);
      }
    }
}

extern "C" void kernel_launch(void* const* d_in, const int* in_sizes, int n_in,
                              void* d_out, int out_size, void* d_ws, size_t ws_size,
                              hipStream_t stream) {
  const float* input = (const float*)d_in[0];
  const float* w_qkv = (const float*)d_in[1];
  const float* b_qkv = (const float*)d_in[2];
  const float* q_scale = (const float*)d_in[3];
  const float* k_scale = (const float*)d_in[4];
  const float* w_out = (const float*)d_in[5];
  const float* b_out = (const float*)d_in[6];
  float* out = (float*)d_out;

  char* ws = (char*)d_ws;
  u16* Abuf  = (u16*)(ws);                // 4096x1024 bf16      (8.39 MB)
  u16* WqkvT = (u16*)(ws + 8388608);      // 3072x1024 bf16      (6.29 MB)
  u16* WoutT = (u16*)(ws + 14680064);     // 1024x1024 bf16      (2.10 MB)
  u16* qkv   = (u16*)(ws + 16777216);     // 4096x3072 bf16      (25.2 MB)
  u16* Qb    = (u16*)(ws + 41943040);     // [32][2048][64] bf16 (8.39 MB)
  u16* Kb    = (u16*)(ws + 50331648);     // [32][2048][64] bf16
  u16* Vt    = (u16*)(ws + 58720256);     // [32][64][2048] bf16
  u16* Attn  = (u16*)(ws + 67108864);     // 4096x1024 bf16

  k_cast<<<2048, 256, 0, stream>>>(input, Abuf);
  k_wtrans<<<dim3(12, 128), 256, 0, stream>>>(w_qkv, WqkvT, 1024, 3072);
  k_wtrans<<<dim3(4, 128), 256, 0, stream>>>(w_out, WoutT, 1024, 1024);
  k_gemm<1><<<dim3(32, 24), 256, 0, stream>>>(Abuf, WqkvT, b_qkv, qkv, 4096, 3072, 1024);
  k_normrope<<<4096, 256, 0, stream>>>(qkv, q_scale, k_scale, Qb, Kb);
  k_vtrans<<<dim3(32, 32), 256, 0, stream>>>(qkv, Vt);
  k_attn<<<dim3(16, 32), 256, 0, stream>>>(Qb, Kb, Vt, Attn);
  k_gemm<0><<<dim3(32, 8), 256, 0, stream>>>(Attn, WoutT, b_out, out, 4096, 1024, 1024);
}

// Round 2
// 146.712 us; speedup vs baseline: 1.4301x; 1.4301x over previous
//
#include <hip/hip_runtime.h>
#include <stdint.h>

typedef short bf16x8 __attribute__((ext_vector_type(8)));
typedef float f32x4 __attribute__((ext_vector_type(4)));
typedef unsigned short u16;

#define MFMA_BF16 __builtin_amdgcn_mfma_f32_16x16x32_bf16
#define LOG2E 1.44269504088896f

static __device__ __forceinline__ u16 f2bf(float x) {
  union { float f; unsigned u; } v; v.f = x;
  unsigned r = v.u + 0x7fffu + ((v.u >> 16) & 1u);
  return (u16)(r >> 16);
}
static __device__ __forceinline__ float bf2f(u16 h) {
  union { unsigned u; float f; } v; v.u = ((unsigned)h) << 16; return v.f;
}
static __device__ __forceinline__ void gld_lds16(const u16* g, u16* l) {
  __builtin_amdgcn_global_load_lds(
      (const __attribute__((address_space(1))) void*)g,
      (__attribute__((address_space(3))) void*)l, 16, 0, 0);
}

// ---------------- cast fp32 -> bf16 (8 elems/thread) ----------------
__global__ __launch_bounds__(256) void k_cast(const float* __restrict__ x,
                                              u16* __restrict__ y) {
  int i = blockIdx.x * 256 + threadIdx.x;
  const float4* p = (const float4*)x;
  float4 a = p[i * 2], b = p[i * 2 + 1];
  ushort4 o0, o1;
  o0.x = f2bf(a.x); o0.y = f2bf(a.y); o0.z = f2bf(a.z); o0.w = f2bf(a.w);
  o1.x = f2bf(b.x); o1.y = f2bf(b.y); o1.z = f2bf(b.z); o1.w = f2bf(b.w);
  ushort4* q = (ushort4*)y;
  q[i * 2] = o0; q[i * 2 + 1] = o1;
}

// ---------------- transpose weight: w[K][N] fp32 -> wt[N][K] bf16 ----------------
__global__ __launch_bounds__(256) void k_wtrans(const float* __restrict__ w,
                                                u16* __restrict__ wt,
                                                int K, int N) {
  int n = blockIdx.x * 256 + threadIdx.x;
  int k0 = blockIdx.y * 8;
  if (n >= N) return;
  u16 o[8];
#pragma unroll
  for (int j = 0; j < 8; j++) o[j] = f2bf(w[(size_t)(k0 + j) * N + n]);
  *(uint4*)&wt[(size_t)n * K + k0] = *(const uint4*)o;
}

// ---------------- GEMM: C[M][N] = A[M][K] * Bt[N][K]^T + bias ----------------
template <int OUT_BF16>
__global__ __launch_bounds__(256, 2) void k_gemm(const u16* __restrict__ A,
                                                 const u16* __restrict__ Bt,
                                                 const float* __restrict__ bias,
                                                 void* __restrict__ Cp,
                                                 int M, int N, int K) {
  __shared__ u16 As[128 * 64];
  __shared__ u16 Bs[128 * 64];
  const int tid = threadIdx.x;
  const int lane = tid & 63;
  const int wid = tid >> 6;
  const int wm = wid >> 1, wn = wid & 1;
  const int m0 = blockIdx.x * 128, n0 = blockIdx.y * 128;

  const int sr = tid >> 3;
  const int sc = tid & 7;
  const int scsw = sc ^ (sr & 7);
  const u16* ga = A + (size_t)(m0 + sr) * K + (scsw << 3);
  const u16* gb = Bt + (size_t)(n0 + sr) * K + (scsw << 3);

  const int ar = wm * 64 + (lane & 15);
  const int br = wn * 64 + (lane & 15);
  const int cs0 = lane >> 4;

  f32x4 acc[4][4] = {};

  for (int k0 = 0; k0 < K; k0 += 64) {
    __syncthreads();
#pragma unroll
    for (int i = 0; i < 4; i++)
      gld_lds16(ga + k0 + i * (32 * K), &As[((tid & ~63) + 256 * i) * 8]);
#pragma unroll
    for (int i = 0; i < 4; i++)
      gld_lds16(gb + k0 + i * (32 * K), &Bs[((tid & ~63) + 256 * i) * 8]);
    __syncthreads();
#pragma unroll
    for (int kk = 0; kk < 2; kk++) {
      bf16x8 af[4], bfr[4];
#pragma unroll
      for (int mi = 0; mi < 4; mi++)
        af[mi] = *(const bf16x8*)&As[(ar + mi * 16) * 64 +
                                     (((kk * 4 + cs0) ^ (ar & 7)) << 3)];
#pragma unroll
      for (int ni = 0; ni < 4; ni++)
        bfr[ni] = *(const bf16x8*)&Bs[(br + ni * 16) * 64 +
                                      (((kk * 4 + cs0) ^ (br & 7)) << 3)];
#pragma unroll
      for (int mi = 0; mi < 4; mi++)
#pragma unroll
        for (int ni = 0; ni < 4; ni++)
          acc[mi][ni] = MFMA_BF16(af[mi], bfr[ni], acc[mi][ni], 0, 0, 0);
    }
  }

  const int crow0 = m0 + wm * 64 + ((lane >> 4) << 2);
  const int ccol0 = n0 + wn * 64 + (lane & 15);
#pragma unroll
  for (int ni = 0; ni < 4; ni++) {
    float bv = bias[ccol0 + ni * 16];
#pragma unroll
    for (int mi = 0; mi < 4; mi++) {
#pragma unroll
      for (int r = 0; r < 4; r++) {
        float v = acc[mi][ni][r] + bv;
        size_t idx = (size_t)(crow0 + mi * 16 + r) * N + ccol0 + ni * 16;
        if (OUT_BF16) ((u16*)Cp)[idx] = f2bf(v);
        else ((float*)Cp)[idx] = v;
      }
    }
  }
}

// ---------------- RMSNorm + RoPE for q,k; writes per-head [bh][n][d] ----------------
__global__ __launch_bounds__(256) void k_normrope(const u16* __restrict__ qkv,
                                                  const float* __restrict__ qscale,
                                                  const float* __restrict__ kscale,
                                                  u16* __restrict__ Qb,
                                                  u16* __restrict__ Kb) {
  const int row = blockIdx.x;  // b*2048+n
  const int b = row >> 11, n = row & 2047;
  const int t = threadIdx.x;
  __shared__ float qn[1024], kn[1024];
  __shared__ float csb[32], snb[32];
  __shared__ float redq[4], redk[4];

  ushort4 q4 = *(const ushort4*)&qkv[(size_t)row * 3072 + t * 4];
  ushort4 k4 = *(const ushort4*)&qkv[(size_t)row * 3072 + 1024 + t * 4];
  float qv[4] = {bf2f(q4.x), bf2f(q4.y), bf2f(q4.z), bf2f(q4.w)};
  float kv[4] = {bf2f(k4.x), bf2f(k4.y), bf2f(k4.z), bf2f(k4.w)};
  float sq = 0.f, sk = 0.f;
#pragma unroll
  for (int j = 0; j < 4; j++) { sq += qv[j] * qv[j]; sk += kv[j] * kv[j]; }
#pragma unroll
  for (int o = 1; o < 64; o <<= 1) {
    sq += __shfl_xor(sq, o);
    sk += __shfl_xor(sk, o);
  }
  if ((t & 63) == 0) { redq[t >> 6] = sq; redk[t >> 6] = sk; }
  if (t < 32) {
    float inv = exp2f(-(float)t * (13.287712379549449f / 32.f)); // 10000^(-t/32)
    float fr = (float)n * inv;
    float s, c;
    sincosf(fr, &s, &c);
    csb[t] = c; snb[t] = s;
  }
  __syncthreads();
  float rq = rsqrtf((redq[0] + redq[1] + redq[2] + redq[3]) * (1.f / 1024.f) + 1e-6f);
  float rk = rsqrtf((redk[0] + redk[1] + redk[2] + redk[3]) * (1.f / 1024.f) + 1e-6f);
#pragma unroll
  for (int j = 0; j < 4; j++) {
    int jj = t * 4 + j;
    qn[jj] = qv[j] * rq * qscale[jj];
    kn[jj] = kv[j] * rk * kscale[jj];
  }
  __syncthreads();
  const int j0 = t * 4;
  const int h = j0 >> 6;
  const int d0 = j0 & 63;
  u16 qo[4], ko[4];
#pragma unroll
  for (int j = 0; j < 4; j++) {
    int jj = j0 + j;
    int dd = d0 + j;
    float c = csb[dd & 31], s = snb[dd & 31];
    float oq, ok;
    if (dd < 32) {
      oq = qn[jj] * c - qn[jj + 32] * s;
      ok = kn[jj] * c - kn[jj + 32] * s;
    } else {
      oq = qn[jj] * c + qn[jj - 32] * s;
      ok = kn[jj] * c + kn[jj - 32] * s;
    }
    qo[j] = f2bf(oq * 0.125f);  // fold logit scale into Q
    ko[j] = f2bf(ok);
  }
  const size_t base = ((size_t)(b * 16 + h) * 2048 + n) * 64 + d0;
  *(ushort4*)&Qb[base] = *(const ushort4*)qo;
  *(ushort4*)&Kb[base] = *(const ushort4*)ko;
}

// ---------------- V transpose per head: qkv v-part -> Vt[bh][d=64][n=2048] ----------------
__global__ __launch_bounds__(256) void k_vtrans(const u16* __restrict__ qkv,
                                                u16* __restrict__ Vt) {
  const int bh = blockIdx.y;
  const int b = bh >> 4, h = bh & 15;
  const int n0 = blockIdx.x * 64;
  const int t = threadIdx.x;
  __shared__ u16 tile[64][72];  // [n][d] padded
#pragma unroll
  for (int i = 0; i < 2; i++) {
    int r = (t >> 3) + 32 * i;
    int c = t & 7;
    uint4 v = *(const uint4*)&qkv[((size_t)(b * 2048 + n0 + r)) * 3072 + 2048 + h * 64 + c * 8];
    *(uint4*)&tile[r][c * 8] = v;
  }
  __syncthreads();
#pragma unroll
  for (int i = 0; i < 2; i++) {
    int dr = (t >> 3) + 32 * i;
    int c = t & 7;
    u16 vals[8];
#pragma unroll
    for (int j = 0; j < 8; j++) vals[j] = tile[c * 8 + j][dr];
    *(uint4*)&Vt[((size_t)bh * 64 + dr) * 2048 + n0 + c * 8] = *(const uint4*)vals;
  }
}

// ---------------- flash attention (v2) ----------------
// 512 threads = 8 waves; wave owns 16 q-rows; BQ=128/block; BKV=64.
// Fixed-max softmax (s bounded by |q||k| <= ~15 after 0.125 fold): p=exp2((s-8)*log2e).
// No max tree, no O rescale; l accumulated lane-locally, one shfl tree at end.
// 1-barrier double-buffered K/V staging: next tile's global_load_lds issued
// before compute, drained by the single end-of-iteration __syncthreads.
__global__ __launch_bounds__(512, 4) void k_attn(const u16* __restrict__ Qb,
                                                 const u16* __restrict__ Kb,
                                                 const u16* __restrict__ Vt,
                                                 u16* __restrict__ Ob) {
  const int bh = blockIdx.y;
  const int q0 = blockIdx.x * 128;
  const int t = threadIdx.x, lane = t & 63, wid = t >> 6;  // wid 0..7
  __shared__ u16 Ks[2][64 * 64];
  __shared__ u16 Vs[2][64 * 64];
  __shared__ u16 Ps[8][16 * 72];
  const u16* Qg = Qb + (size_t)bh * 2048 * 64;
  const u16* Kg = Kb + (size_t)bh * 2048 * 64;
  const u16* Vg = Vt + (size_t)bh * 64 * 2048;

  bf16x8 qf[2];
#pragma unroll
  for (int kk = 0; kk < 2; kk++)
    qf[kk] = *(const bf16x8*)&Qg[(size_t)(q0 + wid * 16 + (lane & 15)) * 64 +
                                 kk * 32 + ((lane >> 4) << 3)];

  f32x4 o[4] = {};
  float lsum[4] = {0.f, 0.f, 0.f, 0.f};

  const int sr = t >> 3;           // 0..63
  const int sc = t & 7;
  const int scsw = sc ^ (sr & 7);
  const u16* gk = Kg + sr * 64 + (scsw << 3);
  const u16* gv = Vg + (size_t)sr * 2048 + (scsw << 3);
  const int cs0 = lane >> 4;
  u16* ldst_k0 = &Ks[0][(t & ~63) * 8];
  u16* ldst_k1 = &Ks[1][(t & ~63) * 8];
  u16* ldst_v0 = &Vs[0][(t & ~63) * 8];
  u16* ldst_v1 = &Vs[1][(t & ~63) * 8];

  // prologue: stage tile 0 into buffer 0
  gld_lds16(gk, ldst_k0);
  gld_lds16(gv, ldst_v0);
  __syncthreads();

  for (int it = 0; it < 32; ++it) {
    const int cur = it & 1;
    if (it < 31) {  // issue next tile's loads; drained by end-of-iter barrier
      const int kv1 = (it + 1) * 64;
      gld_lds16(gk + (size_t)kv1 * 64, cur ? ldst_k0 : ldst_k1);
      gld_lds16(gv + kv1, cur ? ldst_v0 : ldst_v1);
    }
    const u16* Kc = Ks[cur];
    const u16* Vc = Vs[cur];

    // S = Q K^T  (scale pre-folded into Q)
    f32x4 s[4] = {};
#pragma unroll
    for (int kk = 0; kk < 2; kk++) {
      bf16x8 kf[4];
#pragma unroll
      for (int nj = 0; nj < 4; nj++) {
        int kr = nj * 16 + (lane & 15);
        kf[nj] = *(const bf16x8*)&Kc[kr * 64 + (((kk * 4 + cs0) ^ (kr & 7)) << 3)];
      }
#pragma unroll
      for (int nj = 0; nj < 4; nj++)
        s[nj] = MFMA_BF16(qf[kk], kf[nj], s[nj], 0, 0, 0);
    }

    // fixed-max softmax: p = exp2(s*log2e - 8*log2e); lane-local l accumulation
#pragma unroll
    for (int nj = 0; nj < 4; nj++)
#pragma unroll
      for (int r = 0; r < 4; r++) {
        float p = exp2f(s[nj][r] * LOG2E - 8.f * LOG2E);
        lsum[r] += p;
        Ps[wid][(((lane >> 4) << 2) + r) * 72 + nj * 16 + (lane & 15)] = f2bf(p);
      }

    // O += P V
#pragma unroll
    for (int ks = 0; ks < 2; ks++) {
      bf16x8 pa, vb[4];
      pa = *(const bf16x8*)&Ps[wid][(lane & 15) * 72 + ((ks * 4 + cs0) << 3)];
#pragma unroll
      for (int dj = 0; dj < 4; dj++) {
        int vr = dj * 16 + (lane & 15);
        vb[dj] = *(const bf16x8*)&Vc[vr * 64 + (((ks * 4 + cs0) ^ (vr & 7)) << 3)];
      }
#pragma unroll
      for (int dj = 0; dj < 4; dj++)
        o[dj] = MFMA_BF16(pa, vb[dj], o[dj], 0, 0, 0);
    }
    __syncthreads();
  }

  // row sums: reduce across the 16 lanes sharing each row group
#pragma unroll
  for (int st = 1; st < 16; st <<= 1)
#pragma unroll
    for (int r = 0; r < 4; r++) lsum[r] += __shfl_xor(lsum[r], st);

  const int b = bh >> 4, h = bh & 15;
#pragma unroll
  for (int r = 0; r < 4; r++) {
    float invl = 1.f / lsum[r];
    int rowq = q0 + wid * 16 + ((lane >> 4) << 2) + r;
#pragma unroll
    for (int dj = 0; dj < 4; dj++) {
      int col = h * 64 + dj * 16 + (lane & 15);
      Ob[(size_t)(b * 2048 + rowq) * 1024 + col] = f2bf(o[dj][r] * invl);
    }
  }
}

extern "C" void kernel_launch(void* const* d_in, const int* in_sizes, int n_in,
                              void* d_out, int out_size, void* d_ws, size_t ws_size,
                              hipStream_t stream) {
  const float* input = (const float*)d_in[0];
  const float* w_qkv = (const float*)d_in[1];
  const float* b_qkv = (const float*)d_in[2];
  const float* q_scale = (const float*)d_in[3];
  const float* k_scale = (const float*)d_in[4];
  const float* w_out = (const float*)d_in[5];
  const float* b_out = (const float*)d_in[6];
  float* out = (float*)d_out;

  char* ws = (char*)d_ws;
  u16* Abuf  = (u16*)(ws);                // 4096x1024 bf16
  u16* WqkvT = (u16*)(ws + 8388608);      // 3072x1024 bf16
  u16* WoutT = (u16*)(ws + 14680064);     // 1024x1024 bf16
  u16* qkv   = (u16*)(ws + 16777216);     // 4096x3072 bf16
  u16* Qb    = (u16*)(ws + 41943040);     // [32][2048][64] bf16
  u16* Kb    = (u16*)(ws + 50331648);     // [32][2048][64] bf16
  u16* Vt    = (u16*)(ws + 58720256);     // [32][64][2048] bf16
  u16* Attn  = (u16*)(ws + 67108864);     // 4096x1024 bf16

  k_cast<<<2048, 256, 0, stream>>>(input, Abuf);
  k_wtrans<<<dim3(12, 128), 256, 0, stream>>>(w_qkv, WqkvT, 1024, 3072);
  k_wtrans<<<dim3(4, 128), 256, 0, stream>>>(w_out, WoutT, 1024, 1024);
  k_gemm<1><<<dim3(32, 24), 256, 0, stream>>>(Abuf, WqkvT, b_qkv, qkv, 4096, 3072, 1024);
  k_normrope<<<4096, 256, 0, stream>>>(qkv, q_scale, k_scale, Qb, Kb);
  k_vtrans<<<dim3(32, 32), 256, 0, stream>>>(qkv, Vt);
  k_attn<<<dim3(16, 32), 512, 0, stream>>>(Qb, Kb, Vt, Attn);
  k_gemm<0><<<dim3(32, 8), 256, 0, stream>>>(Attn, WoutT, b_out, out, 4096, 1024, 1024);
}

// Round 3
// 140.997 us; speedup vs baseline: 1.4880x; 1.0405x over previous
//
#include <hip/hip_runtime.h>
#include <stdint.h>

typedef short bf16x8 __attribute__((ext_vector_type(8)));
typedef float f32x4 __attribute__((ext_vector_type(4)));
typedef unsigned short u16;

#define MFMA_BF16 __builtin_amdgcn_mfma_f32_16x16x32_bf16
#define LOG2E 1.44269504088896f

static __device__ __forceinline__ u16 f2bf(float x) {
  union { float f; unsigned u; } v; v.f = x;
  unsigned r = v.u + 0x7fffu + ((v.u >> 16) & 1u);
  return (u16)(r >> 16);
}
static __device__ __forceinline__ float bf2f(u16 h) {
  union { unsigned u; float f; } v; v.u = ((unsigned)h) << 16; return v.f;
}
static __device__ __forceinline__ unsigned cvt_pk_bf16(float lo, float hi) {
  unsigned r;
  asm("v_cvt_pk_bf16_f32 %0, %1, %2" : "=v"(r) : "v"(lo), "v"(hi));
  return r;
}
static __device__ __forceinline__ void gld_lds16(const u16* g, u16* l) {
  __builtin_amdgcn_global_load_lds(
      (const __attribute__((address_space(1))) void*)g,
      (__attribute__((address_space(3))) void*)l, 16, 0, 0);
}

// ---------------- cast fp32 -> bf16 (8 elems/thread) ----------------
__global__ __launch_bounds__(256) void k_cast(const float* __restrict__ x,
                                              u16* __restrict__ y) {
  int i = blockIdx.x * 256 + threadIdx.x;
  const float4* p = (const float4*)x;
  float4 a = p[i * 2], b = p[i * 2 + 1];
  ushort4 o0, o1;
  o0.x = f2bf(a.x); o0.y = f2bf(a.y); o0.z = f2bf(a.z); o0.w = f2bf(a.w);
  o1.x = f2bf(b.x); o1.y = f2bf(b.y); o1.z = f2bf(b.z); o1.w = f2bf(b.w);
  ushort4* q = (ushort4*)y;
  q[i * 2] = o0; q[i * 2 + 1] = o1;
}

// ---------------- transpose weight: w[K][N] fp32 -> wt[N][K] bf16 ----------------
__global__ __launch_bounds__(256) void k_wtrans(const float* __restrict__ w,
                                                u16* __restrict__ wt,
                                                int K, int N) {
  int n = blockIdx.x * 256 + threadIdx.x;
  int k0 = blockIdx.y * 8;
  if (n >= N) return;
  u16 o[8];
#pragma unroll
  for (int j = 0; j < 8; j++) o[j] = f2bf(w[(size_t)(k0 + j) * N + n]);
  *(uint4*)&wt[(size_t)n * K + k0] = *(const uint4*)o;
}

// ---------------- GEMM: C[M][N] = A[M][K] * Bt[N][K]^T + bias ----------------
template <int OUT_BF16>
__global__ __launch_bounds__(256, 2) void k_gemm(const u16* __restrict__ A,
                                                 const u16* __restrict__ Bt,
                                                 const float* __restrict__ bias,
                                                 void* __restrict__ Cp,
                                                 int M, int N, int K) {
  __shared__ u16 As[128 * 64];
  __shared__ u16 Bs[128 * 64];
  const int tid = threadIdx.x;
  const int lane = tid & 63;
  const int wid = tid >> 6;
  const int wm = wid >> 1, wn = wid & 1;
  const int m0 = blockIdx.x * 128, n0 = blockIdx.y * 128;

  const int sr = tid >> 3;
  const int sc = tid & 7;
  const int scsw = sc ^ (sr & 7);
  const u16* ga = A + (size_t)(m0 + sr) * K + (scsw << 3);
  const u16* gb = Bt + (size_t)(n0 + sr) * K + (scsw << 3);

  const int ar = wm * 64 + (lane & 15);
  const int br = wn * 64 + (lane & 15);
  const int cs0 = lane >> 4;

  f32x4 acc[4][4] = {};

  for (int k0 = 0; k0 < K; k0 += 64) {
    __syncthreads();
#pragma unroll
    for (int i = 0; i < 4; i++)
      gld_lds16(ga + k0 + i * (32 * K), &As[((tid & ~63) + 256 * i) * 8]);
#pragma unroll
    for (int i = 0; i < 4; i++)
      gld_lds16(gb + k0 + i * (32 * K), &Bs[((tid & ~63) + 256 * i) * 8]);
    __syncthreads();
#pragma unroll
    for (int kk = 0; kk < 2; kk++) {
      bf16x8 af[4], bfr[4];
#pragma unroll
      for (int mi = 0; mi < 4; mi++)
        af[mi] = *(const bf16x8*)&As[(ar + mi * 16) * 64 +
                                     (((kk * 4 + cs0) ^ (ar & 7)) << 3)];
#pragma unroll
      for (int ni = 0; ni < 4; ni++)
        bfr[ni] = *(const bf16x8*)&Bs[(br + ni * 16) * 64 +
                                      (((kk * 4 + cs0) ^ (br & 7)) << 3)];
#pragma unroll
      for (int mi = 0; mi < 4; mi++)
#pragma unroll
        for (int ni = 0; ni < 4; ni++)
          acc[mi][ni] = MFMA_BF16(af[mi], bfr[ni], acc[mi][ni], 0, 0, 0);
    }
  }

  const int crow0 = m0 + wm * 64 + ((lane >> 4) << 2);
  const int ccol0 = n0 + wn * 64 + (lane & 15);
#pragma unroll
  for (int ni = 0; ni < 4; ni++) {
    float bv = bias[ccol0 + ni * 16];
#pragma unroll
    for (int mi = 0; mi < 4; mi++) {
#pragma unroll
      for (int r = 0; r < 4; r++) {
        float v = acc[mi][ni][r] + bv;
        size_t idx = (size_t)(crow0 + mi * 16 + r) * N + ccol0 + ni * 16;
        if (OUT_BF16) ((u16*)Cp)[idx] = f2bf(v);
        else ((float*)Cp)[idx] = v;
      }
    }
  }
}

// ---------------- RMSNorm + RoPE for q,k; writes per-head [bh][n][d] ----------------
__global__ __launch_bounds__(256) void k_normrope(const u16* __restrict__ qkv,
                                                  const float* __restrict__ qscale,
                                                  const float* __restrict__ kscale,
                                                  u16* __restrict__ Qb,
                                                  u16* __restrict__ Kb) {
  const int row = blockIdx.x;  // b*2048+n
  const int b = row >> 11, n = row & 2047;
  const int t = threadIdx.x;
  __shared__ float qn[1024], kn[1024];
  __shared__ float csb[32], snb[32];
  __shared__ float redq[4], redk[4];

  ushort4 q4 = *(const ushort4*)&qkv[(size_t)row * 3072 + t * 4];
  ushort4 k4 = *(const ushort4*)&qkv[(size_t)row * 3072 + 1024 + t * 4];
  float qv[4] = {bf2f(q4.x), bf2f(q4.y), bf2f(q4.z), bf2f(q4.w)};
  float kv[4] = {bf2f(k4.x), bf2f(k4.y), bf2f(k4.z), bf2f(k4.w)};
  float sq = 0.f, sk = 0.f;
#pragma unroll
  for (int j = 0; j < 4; j++) { sq += qv[j] * qv[j]; sk += kv[j] * kv[j]; }
#pragma unroll
  for (int o = 1; o < 64; o <<= 1) {
    sq += __shfl_xor(sq, o);
    sk += __shfl_xor(sk, o);
  }
  if ((t & 63) == 0) { redq[t >> 6] = sq; redk[t >> 6] = sk; }
  if (t < 32) {
    float inv = exp2f(-(float)t * (13.287712379549449f / 32.f)); // 10000^(-t/32)
    float fr = (float)n * inv;
    float s, c;
    sincosf(fr, &s, &c);
    csb[t] = c; snb[t] = s;
  }
  __syncthreads();
  float rq = rsqrtf((redq[0] + redq[1] + redq[2] + redq[3]) * (1.f / 1024.f) + 1e-6f);
  float rk = rsqrtf((redk[0] + redk[1] + redk[2] + redk[3]) * (1.f / 1024.f) + 1e-6f);
#pragma unroll
  for (int j = 0; j < 4; j++) {
    int jj = t * 4 + j;
    qn[jj] = qv[j] * rq * qscale[jj];
    kn[jj] = kv[j] * rk * kscale[jj];
  }
  __syncthreads();
  const int j0 = t * 4;
  const int h = j0 >> 6;
  const int d0 = j0 & 63;
  u16 qo[4], ko[4];
#pragma unroll
  for (int j = 0; j < 4; j++) {
    int jj = j0 + j;
    int dd = d0 + j;
    float c = csb[dd & 31], s = snb[dd & 31];
    float oq, ok;
    if (dd < 32) {
      oq = qn[jj] * c - qn[jj + 32] * s;
      ok = kn[jj] * c - kn[jj + 32] * s;
    } else {
      oq = qn[jj] * c + qn[jj - 32] * s;
      ok = kn[jj] * c + kn[jj - 32] * s;
    }
    qo[j] = f2bf(oq * 0.125f);  // fold logit scale into Q
    ko[j] = f2bf(ok);
  }
  const size_t base = ((size_t)(b * 16 + h) * 2048 + n) * 64 + d0;
  *(ushort4*)&Qb[base] = *(const ushort4*)qo;
  *(ushort4*)&Kb[base] = *(const ushort4*)ko;
}

// ---------------- V transpose per head: qkv v-part -> Vt[bh][d=64][n=2048] ----------------
__global__ __launch_bounds__(256) void k_vtrans(const u16* __restrict__ qkv,
                                                u16* __restrict__ Vt) {
  const int bh = blockIdx.y;
  const int b = bh >> 4, h = bh & 15;
  const int n0 = blockIdx.x * 64;
  const int t = threadIdx.x;
  __shared__ u16 tile[64][72];  // [n][d] padded
#pragma unroll
  for (int i = 0; i < 2; i++) {
    int r = (t >> 3) + 32 * i;
    int c = t & 7;
    uint4 v = *(const uint4*)&qkv[((size_t)(b * 2048 + n0 + r)) * 3072 + 2048 + h * 64 + c * 8];
    *(uint4*)&tile[r][c * 8] = v;
  }
  __syncthreads();
#pragma unroll
  for (int i = 0; i < 2; i++) {
    int dr = (t >> 3) + 32 * i;
    int c = t & 7;
    u16 vals[8];
#pragma unroll
    for (int j = 0; j < 8; j++) vals[j] = tile[c * 8 + j][dr];
    *(uint4*)&Vt[((size_t)bh * 64 + dr) * 2048 + n0 + c * 8] = *(const uint4*)vals;
  }
}

// ---------------- flash attention (v3: swapped-operand, T12) ----------------
// 512 threads = 8 waves; wave owns 16 q-rows; BQ=128/block; BKV=64.
// QK^T computed SWAPPED: s[nj] = mfma(K_frag, Q_frag) -> D[kv][q], so each
// lane owns one q-row (lane&15) and kv = nj*16 + (lane>>4)*4 + r. Softmax is
// fully lane-local: p=exp2((s-8)*log2e), scalar lsum. P packed to bf16 via
// v_cvt_pk (pairs kv-adjacent) -> 4 ds_write_b64. PV computed transposed
// (O^T = V^T P^T): V^T frags read Vs exactly as before; P^T B-frag is one
// contiguous ds_read_b128 per ks. Epilogue: ushort4 stores.
__global__ __launch_bounds__(512, 4) void k_attn(const u16* __restrict__ Qb,
                                                 const u16* __restrict__ Kb,
                                                 const u16* __restrict__ Vt,
                                                 u16* __restrict__ Ob) {
  const int bh = blockIdx.y;
  const int q0 = blockIdx.x * 128;
  const int t = threadIdx.x, lane = t & 63, wid = t >> 6;  // wid 0..7
  __shared__ u16 Ks[2][64 * 64];
  __shared__ u16 Vs[2][64 * 64];
  __shared__ u16 Ps[8][16 * 72];
  const u16* Qg = Qb + (size_t)bh * 2048 * 64;
  const u16* Kg = Kb + (size_t)bh * 2048 * 64;
  const u16* Vg = Vt + (size_t)bh * 64 * 2048;

  const int q = lane & 15;       // this lane's q-row (local)
  const int g = lane >> 4;       // 4-lane column group

  bf16x8 qf[2];
#pragma unroll
  for (int kk = 0; kk < 2; kk++)
    qf[kk] = *(const bf16x8*)&Qg[(size_t)(q0 + wid * 16 + q) * 64 +
                                 kk * 32 + (g << 3)];

  f32x4 ot[4] = {};   // O^T accum: ot[dj][r] = O[q][d = dj*16 + g*4 + r]
  float lsum = 0.f;

  const int sr = t >> 3;           // 0..63
  const int sc = t & 7;
  const int scsw = sc ^ (sr & 7);
  const u16* gk = Kg + sr * 64 + (scsw << 3);
  const u16* gv = Vg + (size_t)sr * 2048 + (scsw << 3);
  u16* ldst_k0 = &Ks[0][(t & ~63) * 8];
  u16* ldst_k1 = &Ks[1][(t & ~63) * 8];
  u16* ldst_v0 = &Vs[0][(t & ~63) * 8];
  u16* ldst_v1 = &Vs[1][(t & ~63) * 8];

  // prologue: stage tile 0 into buffer 0
  gld_lds16(gk, ldst_k0);
  gld_lds16(gv, ldst_v0);
  __syncthreads();

  u16* pr = &Ps[wid][q * 72];

  for (int it = 0; it < 32; ++it) {
    const int cur = it & 1;
    if (it < 31) {  // issue next tile's loads; drained by end-of-iter barrier
      const int kv1 = (it + 1) * 64;
      gld_lds16(gk + (size_t)kv1 * 64, cur ? ldst_k0 : ldst_k1);
      gld_lds16(gv + kv1, cur ? ldst_v0 : ldst_v1);
    }
    const u16* Kc = Ks[cur];
    const u16* Vc = Vs[cur];

    // S^T = K Q^T (swapped): s[nj] holds S[kv = nj*16+g*4+r][q]
    f32x4 s[4] = {};
#pragma unroll
    for (int kk = 0; kk < 2; kk++) {
      bf16x8 kf[4];
#pragma unroll
      for (int nj = 0; nj < 4; nj++) {
        int kr = nj * 16 + q;
        kf[nj] = *(const bf16x8*)&Kc[kr * 64 + (((kk * 4 + g) ^ (kr & 7)) << 3)];
      }
#pragma unroll
      for (int nj = 0; nj < 4; nj++)
        s[nj] = MFMA_BF16(kf[nj], qf[kk], s[nj], 0, 0, 0);
    }

    // fixed-max softmax, lane-local; pack pairs and write b64s
#pragma unroll
    for (int nj = 0; nj < 4; nj++) {
      float p0 = exp2f(s[nj][0] * LOG2E - 8.f * LOG2E);
      float p1 = exp2f(s[nj][1] * LOG2E - 8.f * LOG2E);
      float p2 = exp2f(s[nj][2] * LOG2E - 8.f * LOG2E);
      float p3 = exp2f(s[nj][3] * LOG2E - 8.f * LOG2E);
      lsum += (p0 + p1) + (p2 + p3);
      uint2 w;
      w.x = cvt_pk_bf16(p0, p1);
      w.y = cvt_pk_bf16(p2, p3);
      *(uint2*)&pr[nj * 16 + g * 4] = w;   // kv = nj*16+g*4 .. +3
    }

    // O^T += V^T P^T
#pragma unroll
    for (int ks = 0; ks < 2; ks++) {
      bf16x8 pb = *(const bf16x8*)&pr[ks * 32 + g * 8];
      bf16x8 vb[4];
#pragma unroll
      for (int dj = 0; dj < 4; dj++) {
        int vr = dj * 16 + q;
        vb[dj] = *(const bf16x8*)&Vc[vr * 64 + (((ks * 4 + g) ^ (vr & 7)) << 3)];
      }
#pragma unroll
      for (int dj = 0; dj < 4; dj++)
        ot[dj] = MFMA_BF16(vb[dj], pb, ot[dj], 0, 0, 0);
    }
    __syncthreads();
  }

  // full row sum: combine the 4 column-group lanes holding this q-row
  lsum += __shfl_xor(lsum, 16);
  lsum += __shfl_xor(lsum, 32);
  const float invl = 1.f / lsum;

  const int b = bh >> 4, h = bh & 15;
  const int rowq = q0 + wid * 16 + q;
#pragma unroll
  for (int dj = 0; dj < 4; dj++) {
    u16 ov[4];
#pragma unroll
    for (int r = 0; r < 4; r++) ov[r] = f2bf(ot[dj][r] * invl);
    *(ushort4*)&Ob[(size_t)(b * 2048 + rowq) * 1024 + h * 64 + dj * 16 + g * 4] =
        *(const ushort4*)ov;
  }
}

extern "C" void kernel_launch(void* const* d_in, const int* in_sizes, int n_in,
                              void* d_out, int out_size, void* d_ws, size_t ws_size,
                              hipStream_t stream) {
  const float* input = (const float*)d_in[0];
  const float* w_qkv = (const float*)d_in[1];
  const float* b_qkv = (const float*)d_in[2];
  const float* q_scale = (const float*)d_in[3];
  const float* k_scale = (const float*)d_in[4];
  const float* w_out = (const float*)d_in[5];
  const float* b_out = (const float*)d_in[6];
  float* out = (float*)d_out;

  char* ws = (char*)d_ws;
  u16* Abuf  = (u16*)(ws);                // 4096x1024 bf16
  u16* WqkvT = (u16*)(ws + 8388608);      // 3072x1024 bf16
  u16* WoutT = (u16*)(ws + 14680064);     // 1024x1024 bf16
  u16* qkv   = (u16*)(ws + 16777216);     // 4096x3072 bf16
  u16* Qb    = (u16*)(ws + 41943040);     // [32][2048][64] bf16
  u16* Kb    = (u16*)(ws + 50331648);     // [32][2048][64] bf16
  u16* Vt    = (u16*)(ws + 58720256);     // [32][64][2048] bf16
  u16* Attn  = (u16*)(ws + 67108864);     // 4096x1024 bf16

  k_cast<<<2048, 256, 0, stream>>>(input, Abuf);
  k_wtrans<<<dim3(12, 128), 256, 0, stream>>>(w_qkv, WqkvT, 1024, 3072);
  k_wtrans<<<dim3(4, 128), 256, 0, stream>>>(w_out, WoutT, 1024, 1024);
  k_gemm<1><<<dim3(32, 24), 256, 0, stream>>>(Abuf, WqkvT, b_qkv, qkv, 4096, 3072, 1024);
  k_normrope<<<4096, 256, 0, stream>>>(qkv, q_scale, k_scale, Qb, Kb);
  k_vtrans<<<dim3(32, 32), 256, 0, stream>>>(qkv, Vt);
  k_attn<<<dim3(16, 32), 512, 0, stream>>>(Qb, Kb, Vt, Attn);
  k_gemm<0><<<dim3(32, 8), 256, 0, stream>>>(Attn, WoutT, b_out, out, 4096, 1024, 1024);
}

// Round 4
// 140.520 us; speedup vs baseline: 1.4931x; 1.0034x over previous
//
#include <hip/hip_runtime.h>
#include <stdint.h>

typedef short bf16x8 __attribute__((ext_vector_type(8)));
typedef float f32x4 __attribute__((ext_vector_type(4)));
typedef unsigned short u16;

#define MFMA_BF16 __builtin_amdgcn_mfma_f32_16x16x32_bf16
#define LOG2E 1.44269504088896f

static __device__ __forceinline__ u16 f2bf(float x) {
  union { float f; unsigned u; } v; v.f = x;
  unsigned r = v.u + 0x7fffu + ((v.u >> 16) & 1u);
  return (u16)(r >> 16);
}
static __device__ __forceinline__ float bf2f(u16 h) {
  union { unsigned u; float f; } v; v.u = ((unsigned)h) << 16; return v.f;
}
static __device__ __forceinline__ unsigned cvt_pk_bf16(float lo, float hi) {
  unsigned r;
  asm("v_cvt_pk_bf16_f32 %0, %1, %2" : "=v"(r) : "v"(lo), "v"(hi));
  return r;
}
static __device__ __forceinline__ void gld_lds16(const u16* g, u16* l) {
  __builtin_amdgcn_global_load_lds(
      (const __attribute__((address_space(1))) void*)g,
      (__attribute__((address_space(3))) void*)l, 16, 0, 0);
}

// ---------------- cast fp32 -> bf16 (8 elems/thread) ----------------
__global__ __launch_bounds__(256) void k_cast(const float* __restrict__ x,
                                              u16* __restrict__ y) {
  int i = blockIdx.x * 256 + threadIdx.x;
  const float4* p = (const float4*)x;
  float4 a = p[i * 2], b = p[i * 2 + 1];
  ushort4 o0, o1;
  o0.x = f2bf(a.x); o0.y = f2bf(a.y); o0.z = f2bf(a.z); o0.w = f2bf(a.w);
  o1.x = f2bf(b.x); o1.y = f2bf(b.y); o1.z = f2bf(b.z); o1.w = f2bf(b.w);
  ushort4* q = (ushort4*)y;
  q[i * 2] = o0; q[i * 2 + 1] = o1;
}

// ---------------- transpose weight: w[K][N] fp32 -> wt[N][K] bf16 ----------------
__global__ __launch_bounds__(256) void k_wtrans(const float* __restrict__ w,
                                                u16* __restrict__ wt,
                                                int K, int N) {
  int n = blockIdx.x * 256 + threadIdx.x;
  int k0 = blockIdx.y * 8;
  if (n >= N) return;
  u16 o[8];
#pragma unroll
  for (int j = 0; j < 8; j++) o[j] = f2bf(w[(size_t)(k0 + j) * N + n]);
  *(uint4*)&wt[(size_t)n * K + k0] = *(const uint4*)o;
}

// ---------------- GEMM: C[M][N] = A[M][K] * Bt[N][K]^T + bias ----------------
template <int OUT_BF16>
__global__ __launch_bounds__(256, 2) void k_gemm(const u16* __restrict__ A,
                                                 const u16* __restrict__ Bt,
                                                 const float* __restrict__ bias,
                                                 void* __restrict__ Cp,
                                                 int M, int N, int K) {
  __shared__ u16 As[128 * 64];
  __shared__ u16 Bs[128 * 64];
  const int tid = threadIdx.x;
  const int lane = tid & 63;
  const int wid = tid >> 6;
  const int wm = wid >> 1, wn = wid & 1;
  const int m0 = blockIdx.x * 128, n0 = blockIdx.y * 128;

  const int sr = tid >> 3;
  const int sc = tid & 7;
  const int scsw = sc ^ (sr & 7);
  const u16* ga = A + (size_t)(m0 + sr) * K + (scsw << 3);
  const u16* gb = Bt + (size_t)(n0 + sr) * K + (scsw << 3);

  const int ar = wm * 64 + (lane & 15);
  const int br = wn * 64 + (lane & 15);
  const int cs0 = lane >> 4;

  f32x4 acc[4][4] = {};

  for (int k0 = 0; k0 < K; k0 += 64) {
    __syncthreads();
#pragma unroll
    for (int i = 0; i < 4; i++)
      gld_lds16(ga + k0 + i * (32 * K), &As[((tid & ~63) + 256 * i) * 8]);
#pragma unroll
    for (int i = 0; i < 4; i++)
      gld_lds16(gb + k0 + i * (32 * K), &Bs[((tid & ~63) + 256 * i) * 8]);
    __syncthreads();
#pragma unroll
    for (int kk = 0; kk < 2; kk++) {
      bf16x8 af[4], bfr[4];
#pragma unroll
      for (int mi = 0; mi < 4; mi++)
        af[mi] = *(const bf16x8*)&As[(ar + mi * 16) * 64 +
                                     (((kk * 4 + cs0) ^ (ar & 7)) << 3)];
#pragma unroll
      for (int ni = 0; ni < 4; ni++)
        bfr[ni] = *(const bf16x8*)&Bs[(br + ni * 16) * 64 +
                                      (((kk * 4 + cs0) ^ (br & 7)) << 3)];
#pragma unroll
      for (int mi = 0; mi < 4; mi++)
#pragma unroll
        for (int ni = 0; ni < 4; ni++)
          acc[mi][ni] = MFMA_BF16(af[mi], bfr[ni], acc[mi][ni], 0, 0, 0);
    }
  }

  const int crow0 = m0 + wm * 64 + ((lane >> 4) << 2);
  const int ccol0 = n0 + wn * 64 + (lane & 15);
#pragma unroll
  for (int ni = 0; ni < 4; ni++) {
    float bv = bias[ccol0 + ni * 16];
#pragma unroll
    for (int mi = 0; mi < 4; mi++) {
#pragma unroll
      for (int r = 0; r < 4; r++) {
        float v = acc[mi][ni][r] + bv;
        size_t idx = (size_t)(crow0 + mi * 16 + r) * N + ccol0 + ni * 16;
        if (OUT_BF16) ((u16*)Cp)[idx] = f2bf(v);
        else ((float*)Cp)[idx] = v;
      }
    }
  }
}

// ---------------- RMSNorm + RoPE for q,k; writes per-head [bh][n][d] ----------------
// Q gets 0.125 (logit scale) * log2(e) folded in -> attention uses bare exp2.
__global__ __launch_bounds__(256) void k_normrope(const u16* __restrict__ qkv,
                                                  const float* __restrict__ qscale,
                                                  const float* __restrict__ kscale,
                                                  u16* __restrict__ Qb,
                                                  u16* __restrict__ Kb) {
  const int row = blockIdx.x;  // b*2048+n
  const int b = row >> 11, n = row & 2047;
  const int t = threadIdx.x;
  __shared__ float qn[1024], kn[1024];
  __shared__ float csb[32], snb[32];
  __shared__ float redq[4], redk[4];

  ushort4 q4 = *(const ushort4*)&qkv[(size_t)row * 3072 + t * 4];
  ushort4 k4 = *(const ushort4*)&qkv[(size_t)row * 3072 + 1024 + t * 4];
  float qv[4] = {bf2f(q4.x), bf2f(q4.y), bf2f(q4.z), bf2f(q4.w)};
  float kv[4] = {bf2f(k4.x), bf2f(k4.y), bf2f(k4.z), bf2f(k4.w)};
  float sq = 0.f, sk = 0.f;
#pragma unroll
  for (int j = 0; j < 4; j++) { sq += qv[j] * qv[j]; sk += kv[j] * kv[j]; }
#pragma unroll
  for (int o = 1; o < 64; o <<= 1) {
    sq += __shfl_xor(sq, o);
    sk += __shfl_xor(sk, o);
  }
  if ((t & 63) == 0) { redq[t >> 6] = sq; redk[t >> 6] = sk; }
  if (t < 32) {
    float inv = exp2f(-(float)t * (13.287712379549449f / 32.f)); // 10000^(-t/32)
    float fr = (float)n * inv;
    float s, c;
    sincosf(fr, &s, &c);
    csb[t] = c; snb[t] = s;
  }
  __syncthreads();
  float rq = rsqrtf((redq[0] + redq[1] + redq[2] + redq[3]) * (1.f / 1024.f) + 1e-6f);
  float rk = rsqrtf((redk[0] + redk[1] + redk[2] + redk[3]) * (1.f / 1024.f) + 1e-6f);
#pragma unroll
  for (int j = 0; j < 4; j++) {
    int jj = t * 4 + j;
    qn[jj] = qv[j] * rq * qscale[jj];
    kn[jj] = kv[j] * rk * kscale[jj];
  }
  __syncthreads();
  const int j0 = t * 4;
  const int h = j0 >> 6;
  const int d0 = j0 & 63;
  u16 qo[4], ko[4];
#pragma unroll
  for (int j = 0; j < 4; j++) {
    int jj = j0 + j;
    int dd = d0 + j;
    float c = csb[dd & 31], s = snb[dd & 31];
    float oq, ok;
    if (dd < 32) {
      oq = qn[jj] * c - qn[jj + 32] * s;
      ok = kn[jj] * c - kn[jj + 32] * s;
    } else {
      oq = qn[jj] * c + qn[jj - 32] * s;
      ok = kn[jj] * c + kn[jj - 32] * s;
    }
    qo[j] = f2bf(oq * (0.125f * LOG2E));  // logit scale * log2e, single rounding
    ko[j] = f2bf(ok);
  }
  const size_t base = ((size_t)(b * 16 + h) * 2048 + n) * 64 + d0;
  *(ushort4*)&Qb[base] = *(const ushort4*)qo;
  *(ushort4*)&Kb[base] = *(const ushort4*)ko;
}

// ---------------- V transpose per head: qkv v-part -> Vt[bh][d=64][n=2048] ----------------
__global__ __launch_bounds__(256) void k_vtrans(const u16* __restrict__ qkv,
                                                u16* __restrict__ Vt) {
  const int bh = blockIdx.y;
  const int b = bh >> 4, h = bh & 15;
  const int n0 = blockIdx.x * 64;
  const int t = threadIdx.x;
  __shared__ u16 tile[64][72];  // [n][d] padded
#pragma unroll
  for (int i = 0; i < 2; i++) {
    int r = (t >> 3) + 32 * i;
    int c = t & 7;
    uint4 v = *(const uint4*)&qkv[((size_t)(b * 2048 + n0 + r)) * 3072 + 2048 + h * 64 + c * 8];
    *(uint4*)&tile[r][c * 8] = v;
  }
  __syncthreads();
#pragma unroll
  for (int i = 0; i < 2; i++) {
    int dr = (t >> 3) + 32 * i;
    int c = t & 7;
    u16 vals[8];
#pragma unroll
    for (int j = 0; j < 8; j++) vals[j] = tile[c * 8 + j][dr];
    *(uint4*)&Vt[((size_t)bh * 64 + dr) * 2048 + n0 + c * 8] = *(const uint4*)vals;
  }
}

// ---------------- flash attention (v4: T4 counted-vmcnt pipeline) ----------------
// 512 threads = 8 waves; wave owns 16 q-rows; BQ=128/block; BKV=64.
// Swapped QK^T (lane owns one q-row), lane-local softmax p=exp2(s) (log2e
// pre-folded into Q), P via cvt_pk -> per-wave LDS, PV transposed.
// Pipeline: 2-deep prefetch, counted s_waitcnt vmcnt(2) + raw s_barrier
// (no vmcnt(0) drain in steady state); tile t+2 issued after read-done barrier.
__global__ __launch_bounds__(512, 4) void k_attn(const u16* __restrict__ Qb,
                                                 const u16* __restrict__ Kb,
                                                 const u16* __restrict__ Vt,
                                                 u16* __restrict__ Ob) {
  const int bh = blockIdx.y;
  const int q0 = blockIdx.x * 128;
  const int t = threadIdx.x, lane = t & 63, wid = t >> 6;  // wid 0..7
  __shared__ u16 Ks[2][64 * 64];
  __shared__ u16 Vs[2][64 * 64];
  __shared__ u16 Ps[8][16 * 72];
  const u16* Qg = Qb + (size_t)bh * 2048 * 64;
  const u16* Kg = Kb + (size_t)bh * 2048 * 64;
  const u16* Vg = Vt + (size_t)bh * 64 * 2048;

  const int q = lane & 15;       // this lane's q-row (local)
  const int g = lane >> 4;       // 4-lane column group

  bf16x8 qf[2];
#pragma unroll
  for (int kk = 0; kk < 2; kk++)
    qf[kk] = *(const bf16x8*)&Qg[(size_t)(q0 + wid * 16 + q) * 64 +
                                 kk * 32 + (g << 3)];

  f32x4 ot[4] = {};   // O^T accum: ot[dj][r] = O[q][d = dj*16 + g*4 + r]
  float lsum = 0.f;

  const int sr = t >> 3;           // 0..63
  const int sc = t & 7;
  const int scsw = sc ^ (sr & 7);
  const u16* gk = Kg + sr * 64 + (scsw << 3);
  const u16* gv = Vg + (size_t)sr * 2048 + (scsw << 3);
  u16* ldst_k0 = &Ks[0][(t & ~63) * 8];
  u16* ldst_k1 = &Ks[1][(t & ~63) * 8];
  u16* ldst_v0 = &Vs[0][(t & ~63) * 8];
  u16* ldst_v1 = &Vs[1][(t & ~63) * 8];

  // prologue: stage tile 0 -> buf0, tile 1 -> buf1 (4 loads in flight)
  gld_lds16(gk, ldst_k0);
  gld_lds16(gv, ldst_v0);
  gld_lds16(gk + (size_t)64 * 64, ldst_k1);
  gld_lds16(gv + 64, ldst_v1);

  u16* pr = &Ps[wid][q * 72];

  for (int it = 0; it < 32; ++it) {
    const int cur = it & 1;
    // own oldest tile (it) landed; leave tile it+1's loads in flight
    if (it < 31) asm volatile("s_waitcnt vmcnt(2)" ::: "memory");
    else         asm volatile("s_waitcnt vmcnt(0)" ::: "memory");
    asm volatile("s_barrier" ::: "memory");  // everyone's tile-it data visible

    const u16* Kc = Ks[cur];
    const u16* Vc = Vs[cur];

    // S^T = K Q^T (swapped): s[nj] holds S[kv = nj*16+g*4+r][q]
    f32x4 s[4] = {};
#pragma unroll
    for (int kk = 0; kk < 2; kk++) {
      bf16x8 kf[4];
#pragma unroll
      for (int nj = 0; nj < 4; nj++) {
        int kr = nj * 16 + q;
        kf[nj] = *(const bf16x8*)&Kc[kr * 64 + (((kk * 4 + g) ^ (kr & 7)) << 3)];
      }
      __builtin_amdgcn_s_setprio(1);
#pragma unroll
      for (int nj = 0; nj < 4; nj++)
        s[nj] = MFMA_BF16(kf[nj], qf[kk], s[nj], 0, 0, 0);
      __builtin_amdgcn_s_setprio(0);
    }

    // softmax, lane-local: p = exp2(s) (log2e pre-folded); pack and write b64s
#pragma unroll
    for (int nj = 0; nj < 4; nj++) {
      float p0 = exp2f(s[nj][0]);
      float p1 = exp2f(s[nj][1]);
      float p2 = exp2f(s[nj][2]);
      float p3 = exp2f(s[nj][3]);
      lsum += (p0 + p1) + (p2 + p3);
      uint2 w;
      w.x = cvt_pk_bf16(p0, p1);
      w.y = cvt_pk_bf16(p2, p3);
      *(uint2*)&pr[nj * 16 + g * 4] = w;   // kv = nj*16+g*4 .. +3
    }

    // O^T += V^T P^T
#pragma unroll
    for (int ks = 0; ks < 2; ks++) {
      bf16x8 pb = *(const bf16x8*)&pr[ks * 32 + g * 8];
      bf16x8 vb[4];
#pragma unroll
      for (int dj = 0; dj < 4; dj++) {
        int vr = dj * 16 + q;
        vb[dj] = *(const bf16x8*)&Vc[vr * 64 + (((ks * 4 + g) ^ (vr & 7)) << 3)];
      }
      __builtin_amdgcn_s_setprio(1);
#pragma unroll
      for (int dj = 0; dj < 4; dj++)
        ot[dj] = MFMA_BF16(vb[dj], pb, ot[dj], 0, 0, 0);
      __builtin_amdgcn_s_setprio(0);
    }

    asm volatile("s_barrier" ::: "memory");  // all waves done reading buf[cur]
    if (it < 30) {
      const int kv2 = (it + 2) * 64;
      gld_lds16(gk + (size_t)kv2 * 64, cur ? ldst_k1 : ldst_k0);
      gld_lds16(gv + kv2, cur ? ldst_v1 : ldst_v0);
    }
  }

  // full row sum: combine the 4 column-group lanes holding this q-row
  lsum += __shfl_xor(lsum, 16);
  lsum += __shfl_xor(lsum, 32);
  const float invl = 1.f / lsum;

  const int b = bh >> 4, h = bh & 15;
  const int rowq = q0 + wid * 16 + q;
#pragma unroll
  for (int dj = 0; dj < 4; dj++) {
    u16 ov[4];
#pragma unroll
    for (int r = 0; r < 4; r++) ov[r] = f2bf(ot[dj][r] * invl);
    *(ushort4*)&Ob[(size_t)(b * 2048 + rowq) * 1024 + h * 64 + dj * 16 + g * 4] =
        *(const ushort4*)ov;
  }
}

extern "C" void kernel_launch(void* const* d_in, const int* in_sizes, int n_in,
                              void* d_out, int out_size, void* d_ws, size_t ws_size,
                              hipStream_t stream) {
  const float* input = (const float*)d_in[0];
  const float* w_qkv = (const float*)d_in[1];
  const float* b_qkv = (const float*)d_in[2];
  const float* q_scale = (const float*)d_in[3];
  const float* k_scale = (const float*)d_in[4];
  const float* w_out = (const float*)d_in[5];
  const float* b_out = (const float*)d_in[6];
  float* out = (float*)d_out;

  char* ws = (char*)d_ws;
  u16* Abuf  = (u16*)(ws);                // 4096x1024 bf16
  u16* WqkvT = (u16*)(ws + 8388608);      // 3072x1024 bf16
  u16* WoutT = (u16*)(ws + 14680064);     // 1024x1024 bf16
  u16* qkv   = (u16*)(ws + 16777216);     // 4096x3072 bf16
  u16* Qb    = (u16*)(ws + 41943040);     // [32][2048][64] bf16
  u16* Kb    = (u16*)(ws + 50331648);     // [32][2048][64] bf16
  u16* Vt    = (u16*)(ws + 58720256);     // [32][64][2048] bf16
  u16* Attn  = (u16*)(ws + 67108864);     // 4096x1024 bf16

  k_cast<<<2048, 256, 0, stream>>>(input, Abuf);
  k_wtrans<<<dim3(12, 128), 256, 0, stream>>>(w_qkv, WqkvT, 1024, 3072);
  k_wtrans<<<dim3(4, 128), 256, 0, stream>>>(w_out, WoutT, 1024, 1024);
  k_gemm<1><<<dim3(32, 24), 256, 0, stream>>>(Abuf, WqkvT, b_qkv, qkv, 4096, 3072, 1024);
  k_normrope<<<4096, 256, 0, stream>>>(qkv, q_scale, k_scale, Qb, Kb);
  k_vtrans<<<dim3(32, 32), 256, 0, stream>>>(qkv, Vt);
  k_attn<<<dim3(16, 32), 512, 0, stream>>>(Qb, Kb, Vt, Attn);
  k_gemm<0><<<dim3(32, 8), 256, 0, stream>>>(Attn, WoutT, b_out, out, 4096, 1024, 1024);
}